// Round 3
// baseline (391.603 us; speedup 1.0000x reference)
//
#include <hip/hip_runtime.h>
#include <hip/hip_bf16.h>
#include <stdint.h>

typedef __attribute__((ext_vector_type(8))) short short8;
typedef __attribute__((ext_vector_type(4))) short s16x4;
typedef __attribute__((ext_vector_type(4))) float floatx4;
typedef __attribute__((ext_vector_type(4))) unsigned short ushortx4;

#define T_LEN 2048
#define C_DIM 1024
#define NH 16
#define HD 64

static __device__ __forceinline__ unsigned short f2bf(float f) {
  union { float f; unsigned u; } v; v.f = f;
  unsigned r = v.u + 0x7fffu + ((v.u >> 16) & 1u);
  return (unsigned short)(r >> 16);
}

static __device__ __forceinline__ void stage16(const void* g, void* l) {
  __builtin_amdgcn_global_load_lds(
      (const __attribute__((address_space(1))) void*)g,
      (__attribute__((address_space(3))) void*)l, 16, 0, 0);
}

// 16x16x16 bf16 MFMA via inline asm (A,B = 2 VGPRs each, C/D = 4; D==C in place)
static __device__ __forceinline__ floatx4 mfma16(s16x4 a, s16x4 b, floatx4 c) {
  asm("v_mfma_f32_16x16x16_bf16 %0, %1, %2, %0" : "+v"(c) : "v"(a), "v"(b));
  return c;
}
// pack 2 f32 -> 1 dword of 2 bf16 (lo = s0, hi = s1)
static __device__ __forceinline__ unsigned cvt_pk_bf16(float lo, float hi) {
  unsigned r;
  asm("v_cvt_pk_bf16_f32 %0, %1, %2" : "=v"(r) : "v"(lo), "v"(hi));
  return r;
}

// ---------------- cast x (f32 -> bf16), 4 elems/thread ----------------
__global__ __launch_bounds__(256) void cast_x(const float* __restrict__ in,
                                              unsigned short* __restrict__ out) {
  const long i = (long)(blockIdx.x * 256 + threadIdx.x) * 4;
  const float4 v = *(const float4*)(in + i);
  ushortx4 o;
  o[0] = f2bf(v.x); o[1] = f2bf(v.y); o[2] = f2bf(v.z); o[3] = f2bf(v.w);
  *(ushortx4*)(out + i) = o;
}

// ---------- transpose + cast: in [R][C] f32 -> out [C][R] bf16 ----------
__global__ __launch_bounds__(256) void transpose_cast(
    const float* __restrict__ in, unsigned short* __restrict__ out, int R, int C) {
  __shared__ unsigned short tile[64][72];
  const int r0 = blockIdx.y * 64;
  const int c0 = blockIdx.x * 64;
  const int tid = threadIdx.x;
#pragma unroll
  for (int e = 0; e < 4; ++e) {
    const int ch = e * 256 + tid;           // 1024 chunks of 4 floats
    const int r = ch >> 4, c4 = (ch & 15) * 4;
    const float4 v = *(const float4*)(in + (long)(r0 + r) * C + c0 + c4);
    tile[r][c4 + 0] = f2bf(v.x);
    tile[r][c4 + 1] = f2bf(v.y);
    tile[r][c4 + 2] = f2bf(v.z);
    tile[r][c4 + 3] = f2bf(v.w);
  }
  __syncthreads();
#pragma unroll
  for (int e = 0; e < 2; ++e) {
    const int ch = e * 256 + tid;           // 512 chunks of 8
    const int c = ch >> 3, k8 = (ch & 7) * 8;
    short8 w;
#pragma unroll
    for (int j = 0; j < 8; ++j) w[j] = (short)tile[k8 + j][c];
    *(short8*)(out + (long)(c0 + c) * R + r0 + k8) = w;
  }
}

// ---- V transpose (bf16): [bh][T][D] -> [bh][D][T], 64x64 tiles ----
__global__ __launch_bounds__(256) void vtrans(
    const unsigned short* __restrict__ in, unsigned short* __restrict__ out) {
  __shared__ unsigned short tile[64][72];
  const int bh = blockIdx.y;
  const int t0 = blockIdx.x * 64;
  const int tid = threadIdx.x;
  const unsigned short* src = in + (long)bh * T_LEN * HD + (long)t0 * HD;
#pragma unroll
  for (int e = 0; e < 2; ++e) {
    const int ch = e * 256 + tid;
    const int r = ch >> 3, c8 = (ch & 7) * 8;
    *(short8*)&tile[r][c8] = *(const short8*)(src + r * HD + c8);
  }
  __syncthreads();
  unsigned short* dst = out + (long)bh * HD * T_LEN + t0;
#pragma unroll
  for (int e = 0; e < 2; ++e) {
    const int ch = e * 256 + tid;
    const int d = ch >> 3, t8 = (ch & 7) * 8;
    short8 w;
#pragma unroll
    for (int j = 0; j < 8; ++j) w[j] = (short)tile[t8 + j][d];
    *(short8*)(dst + (long)d * T_LEN + t8) = w;
  }
}

// ---------------- GEMM: C = A[M,K] * Bt[N,K]^T + bias ----------------
// 128x128 tile, BK=32, 256 threads (4 waves, 2x2 of 64x64 subtiles).
// MODE 0: scatter to Q/K/V head layouts (Q scaled by 0.125), bf16 out.
// MODE 1: fp32 out row-major [M][N].
template <int MODE>
__global__ __launch_bounds__(256) void gemm_bt(
    const unsigned short* __restrict__ A,
    const unsigned short* __restrict__ Bt,
    const float* __restrict__ bias,
    int M, int N, int K,
    unsigned short* __restrict__ q_out,
    unsigned short* __restrict__ k_out,
    unsigned short* __restrict__ v_out,
    float* __restrict__ f_out) {
  __shared__ unsigned short As[128 * 32];
  __shared__ unsigned short Bs[128 * 32];
  const int tid = threadIdx.x;
  const int lane = tid & 63;
  const int wid = tid >> 6;
  const int wr = wid >> 1, wc = wid & 1;
  const int lrow = lane & 15, lgrp = lane >> 4;
  const long row0 = (long)blockIdx.y * 128;
  const long col0 = (long)blockIdx.x * 128;

  floatx4 acc[4][4];
#pragma unroll
  for (int m = 0; m < 4; ++m)
#pragma unroll
    for (int n = 0; n < 4; ++n)
      acc[m][n] = (floatx4){0.f, 0.f, 0.f, 0.f};

  const unsigned short* Abase = A + row0 * K;
  const unsigned short* Bbase = Bt + col0 * K;

  for (int k0 = 0; k0 < K; k0 += 32) {
#pragma unroll
    for (int r = 0; r < 2; ++r) {
      const int ch = r * 256 + tid;        // 16B chunk id in [0,512)
      const int trow = ch >> 2, tcol = (ch & 3) * 8;
      stage16(Abase + (long)trow * K + k0 + tcol, &As[(r * 256 + wid * 64) * 8]);
      stage16(Bbase + (long)trow * K + k0 + tcol, &Bs[(r * 256 + wid * 64) * 8]);
    }
    __syncthreads();
    short8 af[4], bf[4];
#pragma unroll
    for (int m = 0; m < 4; ++m)
      af[m] = *(const short8*)&As[(wr * 64 + m * 16 + lrow) * 32 + lgrp * 8];
#pragma unroll
    for (int n = 0; n < 4; ++n)
      bf[n] = *(const short8*)&Bs[(wc * 64 + n * 16 + lrow) * 32 + lgrp * 8];
#pragma unroll
    for (int m = 0; m < 4; ++m)
#pragma unroll
      for (int n = 0; n < 4; ++n)
        acc[m][n] = __builtin_amdgcn_mfma_f32_16x16x32_bf16(af[m], bf[n], acc[m][n], 0, 0, 0);
    __syncthreads();
  }

  if (MODE == 0) {
#pragma unroll
    for (int n = 0; n < 4; ++n) {
      const int c = (int)col0 + wc * 64 + n * 16 + lrow;
      const float bs = bias[c];
      const int sect = c >> 10;            // 0=Q 1=K 2=V
      const int h = (c & 1023) >> 6;
      const int d = c & 63;
      unsigned short* dst = sect == 0 ? q_out : (sect == 1 ? k_out : v_out);
      const float scl = sect == 0 ? 0.125f : 1.0f;  // fold 1/sqrt(64) into Q
#pragma unroll
      for (int m = 0; m < 4; ++m) {
#pragma unroll
        for (int i = 0; i < 4; ++i) {
          const long r = row0 + wr * 64 + m * 16 + lgrp * 4 + i;
          const long b = r >> 11;          // r / 2048
          const long t = r & 2047;
          const float val = (acc[m][n][i] + bs) * scl;
          dst[((b * NH + h) * T_LEN + t) * HD + d] = f2bf(val);
        }
      }
    }
  } else {
#pragma unroll
    for (int n = 0; n < 4; ++n) {
      const int c = (int)col0 + wc * 64 + n * 16 + lrow;
      const float bs = bias[c];
#pragma unroll
      for (int m = 0; m < 4; ++m) {
#pragma unroll
        for (int i = 0; i < 4; ++i) {
          const long r = row0 + wr * 64 + m * 16 + lgrp * 4 + i;
          f_out[r * (long)N + c] = acc[m][n][i] + bs;
        }
      }
    }
  }
}

// ---------------- flash attention v3: 1 wave / 32 q-rows, swapped QK^T ----------------
// Q pre-scaled by 1/8. K [bh][T][D], Vt [bh][D][T]. Out attn [B][T][C] bf16.
// S^T = mfma(K_frag, Q_frag): lane holds S[q=lane&15][s=16sc+4lg+i] -> row-local
// softmax (15 fmax in-reg + 2 shfl_xor). P fragment feeds 16x16x16 PV MFMA
// directly (A-frag layout == softmax layout), no LDS at all.
__global__ __launch_bounds__(64) void attn_fwd(
    const unsigned short* __restrict__ Qb,
    const unsigned short* __restrict__ Kb,
    const unsigned short* __restrict__ Vt,
    unsigned short* __restrict__ attn) {
  const int bh = blockIdx.y;
  const int qt = (int)(gridDim.x - 1 - blockIdx.x);  // reversed: long blocks first
  const int b = bh >> 4, h = bh & 15;
  const int lane = (int)threadIdx.x;
  const int lrow = lane & 15, lgrp = lane >> 4;
  const int q0 = qt * 32;

  const unsigned short* Qh = Qb + (long)bh * T_LEN * HD;
  const unsigned short* Kh = Kb + (long)bh * T_LEN * HD;
  const unsigned short* Vh = Vt + (long)bh * HD * T_LEN;

  // Q fragments (used as the B operand of the swapped QK^T): [qsub][kk]
  short8 aq[2][2];
#pragma unroll
  for (int qs = 0; qs < 2; ++qs)
#pragma unroll
    for (int kk = 0; kk < 2; ++kk)
      aq[qs][kk] = *(const short8*)(Qh + (long)(q0 + qs * 16 + lrow) * HD + kk * 32 + lgrp * 8);

  float m_i[2] = {-1e30f, -1e30f};
  float s_i[2] = {0.f, 0.f};
  floatx4 o[2][4];                               // O[q=16qs+4lg+i][d=16d0+lrow]
#pragma unroll
  for (int qs = 0; qs < 2; ++qs)
#pragma unroll
    for (int d0 = 0; d0 < 4; ++d0) o[qs][d0] = (floatx4){0.f, 0.f, 0.f, 0.f};

  const int send = q0 + 32;                      // causal extent (exclusive)
  for (int s0 = 0; s0 < send; s0 += 64) {
    // ---- QK^T (swapped): sf[qs][sc][i] = S[q=q0+16qs+lrow][s=s0+16sc+4lg+i] ----
    floatx4 sf[2][4];
#pragma unroll
    for (int qs = 0; qs < 2; ++qs)
#pragma unroll
      for (int sc = 0; sc < 4; ++sc) sf[qs][sc] = (floatx4){0.f, 0.f, 0.f, 0.f};
#pragma unroll
    for (int sc = 0; sc < 4; ++sc) {
#pragma unroll
      for (int kk = 0; kk < 2; ++kk) {
        const short8 kf = *(const short8*)(Kh + (long)(s0 + sc * 16 + lrow) * HD + kk * 32 + lgrp * 8);
        sf[0][sc] = __builtin_amdgcn_mfma_f32_16x16x32_bf16(kf, aq[0][kk], sf[0][sc], 0, 0, 0);
        sf[1][sc] = __builtin_amdgcn_mfma_f32_16x16x32_bf16(kf, aq[1][kk], sf[1][sc], 0, 0, 0);
      }
    }
    // ---- causal mask (only near diagonal): s = row-space, q = col-space ----
    if (s0 + 64 > q0) {
#pragma unroll
      for (int qs = 0; qs < 2; ++qs) {
#pragma unroll
        for (int sc = 0; sc < 4; ++sc) {
          const int q = q0 + qs * 16 + lrow;
#pragma unroll
          for (int i = 0; i < 4; ++i) {
            const int s = s0 + sc * 16 + lgrp * 4 + i;
            if (s > q) sf[qs][sc][i] = -1e30f;
          }
        }
      }
    }
    // ---- online softmax: row is lane-local (16 values) + 2-step lgrp butterfly ----
    s16x4 pa[2][4];
#pragma unroll
    for (int qs = 0; qs < 2; ++qs) {
      float m0 = fmaxf(fmaxf(sf[qs][0][0], sf[qs][0][1]), fmaxf(sf[qs][0][2], sf[qs][0][3]));
      float m1 = fmaxf(fmaxf(sf[qs][1][0], sf[qs][1][1]), fmaxf(sf[qs][1][2], sf[qs][1][3]));
      float m2 = fmaxf(fmaxf(sf[qs][2][0], sf[qs][2][1]), fmaxf(sf[qs][2][2], sf[qs][2][3]));
      float m3 = fmaxf(fmaxf(sf[qs][3][0], sf[qs][3][1]), fmaxf(sf[qs][3][2], sf[qs][3][3]));
      float m0123 = fmaxf(fmaxf(m0, m1), fmaxf(m2, m3));
      m0123 = fmaxf(m0123, __shfl_xor(m0123, 16));
      m0123 = fmaxf(m0123, __shfl_xor(m0123, 32));
      const float mnew = fmaxf(m_i[qs], m0123);
      const float scale = __expf(m_i[qs] - mnew);
      float rs = 0.f;
#pragma unroll
      for (int sc = 0; sc < 4; ++sc) {
#pragma unroll
        for (int i = 0; i < 4; ++i) {
          const float pv = __expf(sf[qs][sc][i] - mnew);
          sf[qs][sc][i] = pv;
          rs += pv;
        }
      }
      rs += __shfl_xor(rs, 16);
      rs += __shfl_xor(rs, 32);
      m_i[qs] = mnew;
      s_i[qs] = s_i[qs] * scale + rs;
      // broadcast scale from lrow-space to (lg,i)-space, rescale O
#pragma unroll
      for (int i = 0; i < 4; ++i) {
        const float sbc = __shfl(scale, 4 * lgrp + i);
#pragma unroll
        for (int d0 = 0; d0 < 4; ++d0) o[qs][d0][i] *= sbc;
      }
      // pack P to bf16 A-fragments of the 16x16x16 MFMA (layout already matches)
#pragma unroll
      for (int sc = 0; sc < 4; ++sc) {
        union { unsigned u[2]; s16x4 v; } tmp;
        tmp.u[0] = cvt_pk_bf16(sf[qs][sc][0], sf[qs][sc][1]);
        tmp.u[1] = cvt_pk_bf16(sf[qs][sc][2], sf[qs][sc][3]);
        pa[qs][sc] = tmp.v;
      }
    }
    // ---- PV: O[q][d] += sum_sc P_frag[sc] x V_frag[sc] (16x16x16) ----
#pragma unroll
    for (int d0 = 0; d0 < 4; ++d0) {
#pragma unroll
      for (int sc = 0; sc < 4; ++sc) {
        const s16x4 vb = *(const s16x4*)(Vh + (long)(d0 * 16 + lrow) * T_LEN + s0 + sc * 16 + lgrp * 4);
        o[0][d0] = mfma16(pa[0][sc], vb, o[0][d0]);
        o[1][d0] = mfma16(pa[1][sc], vb, o[1][d0]);
      }
    }
  }
  // ---- epilogue ----
#pragma unroll
  for (int qs = 0; qs < 2; ++qs) {
    float inv[4];
#pragma unroll
    for (int i = 0; i < 4; ++i) inv[i] = 1.0f / __shfl(s_i[qs], 4 * lgrp + i);
#pragma unroll
    for (int d0 = 0; d0 < 4; ++d0) {
#pragma unroll
      for (int i = 0; i < 4; ++i) {
        const int q = q0 + qs * 16 + lgrp * 4 + i;
        attn[(long)(b * T_LEN + q) * C_DIM + h * HD + d0 * 16 + lrow] = f2bf(o[qs][d0][i] * inv[i]);
      }
    }
  }
}

extern "C" void kernel_launch(void* const* d_in, const int* in_sizes, int n_in,
                              void* d_out, int out_size, void* d_ws, size_t ws_size,
                              hipStream_t stream) {
  const float* x     = (const float*)d_in[0];
  const float* Wqkv  = (const float*)d_in[1];
  const float* bqkv  = (const float*)d_in[2];
  const float* Wproj = (const float*)d_in[3];
  const float* bproj = (const float*)d_in[4];
  float* out = (float*)d_out;
  char* ws = (char*)d_ws;
  const size_t MB = 1024 * 1024;
  unsigned short* Qb     = (unsigned short*)(ws + 0 * MB);   // [B,N,T,D] bf16, pre-scaled 1/8
  unsigned short* Kb     = (unsigned short*)(ws + 8 * MB);   // [B,N,T,D]
  unsigned short* Vb     = (unsigned short*)(ws + 16 * MB);  // [B,N,T,D]
  unsigned short* Vt     = (unsigned short*)(ws + 24 * MB);  // [B,N,D,T]
  unsigned short* attn   = (unsigned short*)(ws + 32 * MB);  // [B,T,C]
  unsigned short* xbf    = (unsigned short*)(ws + 40 * MB);  // [B*T,C]
  unsigned short* Wqkvt  = (unsigned short*)(ws + 48 * MB);  // [3C,C]
  unsigned short* Wprojt = (unsigned short*)(ws + 54 * MB);  // [C,C]

  cast_x<<<4096, 256, 0, stream>>>(x, xbf);
  transpose_cast<<<dim3(48, 16), 256, 0, stream>>>(Wqkv, Wqkvt, 1024, 3072);
  transpose_cast<<<dim3(16, 16), 256, 0, stream>>>(Wproj, Wprojt, 1024, 1024);
  gemm_bt<0><<<dim3(24, 32), 256, 0, stream>>>(xbf, Wqkvt, bqkv, 4096, 3072, 1024,
                                               Qb, Kb, Vb, nullptr);
  vtrans<<<dim3(32, 32), 256, 0, stream>>>(Vb, Vt);
  attn_fwd<<<dim3(64, 32), 64, 0, stream>>>(Qb, Kb, Vt, attn);
  gemm_bt<1><<<dim3(8, 32), 256, 0, stream>>>(attn, Wprojt, bproj, 4096, 1024, 1024,
                                              nullptr, nullptr, nullptr, out);
}

// Round 4
// 271.378 us; speedup vs baseline: 1.4430x; 1.4430x over previous
//
#include <hip/hip_runtime.h>
#include <hip/hip_bf16.h>
#include <stdint.h>

typedef __attribute__((ext_vector_type(8))) short short8;
typedef __attribute__((ext_vector_type(4))) short s16x4;
typedef __attribute__((ext_vector_type(4))) float floatx4;
typedef __attribute__((ext_vector_type(4))) unsigned short ushortx4;

#define T_LEN 2048
#define C_DIM 1024
#define NH 16
#define HD 64

static __device__ __forceinline__ unsigned short f2bf(float f) {
  union { float f; unsigned u; } v; v.f = f;
  unsigned r = v.u + 0x7fffu + ((v.u >> 16) & 1u);
  return (unsigned short)(r >> 16);
}

static __device__ __forceinline__ void stage16(const void* g, void* l) {
  __builtin_amdgcn_global_load_lds(
      (const __attribute__((address_space(1))) void*)g,
      (__attribute__((address_space(3))) void*)l, 16, 0, 0);
}

// 16x16x16 bf16 MFMA via inline asm (A,B = 2 VGPRs each, C/D = 4; D==C in place)
static __device__ __forceinline__ floatx4 mfma16(s16x4 a, s16x4 b, floatx4 c) {
  asm("v_mfma_f32_16x16x16_bf16 %0, %1, %2, %0" : "+v"(c) : "v"(a), "v"(b));
  return c;
}
// pack 2 f32 -> 1 dword of 2 bf16 (lo = s0, hi = s1)
static __device__ __forceinline__ unsigned cvt_pk_bf16(float lo, float hi) {
  unsigned r;
  asm("v_cvt_pk_bf16_f32 %0, %1, %2" : "=v"(r) : "v"(lo), "v"(hi));
  return r;
}

// ---------------- cast x (f32 -> bf16), 4 elems/thread ----------------
__global__ __launch_bounds__(256) void cast_x(const float* __restrict__ in,
                                              unsigned short* __restrict__ out) {
  const long i = (long)(blockIdx.x * 256 + threadIdx.x) * 4;
  const float4 v = *(const float4*)(in + i);
  ushortx4 o;
  o[0] = f2bf(v.x); o[1] = f2bf(v.y); o[2] = f2bf(v.z); o[3] = f2bf(v.w);
  *(ushortx4*)(out + i) = o;
}

// ---------- transpose + cast: in [R][C] f32 -> out [C][R] bf16 ----------
__global__ __launch_bounds__(256) void transpose_cast(
    const float* __restrict__ in, unsigned short* __restrict__ out, int R, int C) {
  __shared__ unsigned short tile[64][72];
  const int r0 = blockIdx.y * 64;
  const int c0 = blockIdx.x * 64;
  const int tid = threadIdx.x;
#pragma unroll
  for (int e = 0; e < 4; ++e) {
    const int ch = e * 256 + tid;           // 1024 chunks of 4 floats
    const int r = ch >> 4, c4 = (ch & 15) * 4;
    const float4 v = *(const float4*)(in + (long)(r0 + r) * C + c0 + c4);
    tile[r][c4 + 0] = f2bf(v.x);
    tile[r][c4 + 1] = f2bf(v.y);
    tile[r][c4 + 2] = f2bf(v.z);
    tile[r][c4 + 3] = f2bf(v.w);
  }
  __syncthreads();
#pragma unroll
  for (int e = 0; e < 2; ++e) {
    const int ch = e * 256 + tid;           // 512 chunks of 8
    const int c = ch >> 3, k8 = (ch & 7) * 8;
    short8 w;
#pragma unroll
    for (int j = 0; j < 8; ++j) w[j] = (short)tile[k8 + j][c];
    *(short8*)(out + (long)(c0 + c) * R + r0 + k8) = w;
  }
}

// ---- V transpose (bf16): [bh][T][D] -> [bh][D][T], 64x64 tiles ----
__global__ __launch_bounds__(256) void vtrans(
    const unsigned short* __restrict__ in, unsigned short* __restrict__ out) {
  __shared__ unsigned short tile[64][72];
  const int bh = blockIdx.y;
  const int t0 = blockIdx.x * 64;
  const int tid = threadIdx.x;
  const unsigned short* src = in + (long)bh * T_LEN * HD + (long)t0 * HD;
#pragma unroll
  for (int e = 0; e < 2; ++e) {
    const int ch = e * 256 + tid;
    const int r = ch >> 3, c8 = (ch & 7) * 8;
    *(short8*)&tile[r][c8] = *(const short8*)(src + r * HD + c8);
  }
  __syncthreads();
  unsigned short* dst = out + (long)bh * HD * T_LEN + t0;
#pragma unroll
  for (int e = 0; e < 2; ++e) {
    const int ch = e * 256 + tid;
    const int d = ch >> 3, t8 = (ch & 7) * 8;
    short8 w;
#pragma unroll
    for (int j = 0; j < 8; ++j) w[j] = (short)tile[t8 + j][d];
    *(short8*)(dst + (long)d * T_LEN + t8) = w;
  }
}

// ---------------- GEMM: C = A[M,K] * Bt[N,K]^T + bias ----------------
// 128x128 tile, BK=32, 256 threads (4 waves, 2x2 of 64x64 subtiles).
// MODE 0: scatter to Q/K/V head layouts (Q scaled by 0.125), bf16 out.
// MODE 1: fp32 out row-major [M][N].
template <int MODE>
__global__ __launch_bounds__(256) void gemm_bt(
    const unsigned short* __restrict__ A,
    const unsigned short* __restrict__ Bt,
    const float* __restrict__ bias,
    int M, int N, int K,
    unsigned short* __restrict__ q_out,
    unsigned short* __restrict__ k_out,
    unsigned short* __restrict__ v_out,
    float* __restrict__ f_out) {
  __shared__ unsigned short As[128 * 32];
  __shared__ unsigned short Bs[128 * 32];
  const int tid = threadIdx.x;
  const int lane = tid & 63;
  const int wid = tid >> 6;
  const int wr = wid >> 1, wc = wid & 1;
  const int lrow = lane & 15, lgrp = lane >> 4;
  const long row0 = (long)blockIdx.y * 128;
  const long col0 = (long)blockIdx.x * 128;

  floatx4 acc[4][4];
#pragma unroll
  for (int m = 0; m < 4; ++m)
#pragma unroll
    for (int n = 0; n < 4; ++n)
      acc[m][n] = (floatx4){0.f, 0.f, 0.f, 0.f};

  const unsigned short* Abase = A + row0 * K;
  const unsigned short* Bbase = Bt + col0 * K;

  for (int k0 = 0; k0 < K; k0 += 32) {
#pragma unroll
    for (int r = 0; r < 2; ++r) {
      const int ch = r * 256 + tid;        // 16B chunk id in [0,512)
      const int trow = ch >> 2, tcol = (ch & 3) * 8;
      stage16(Abase + (long)trow * K + k0 + tcol, &As[(r * 256 + wid * 64) * 8]);
      stage16(Bbase + (long)trow * K + k0 + tcol, &Bs[(r * 256 + wid * 64) * 8]);
    }
    __syncthreads();
    short8 af[4], bf[4];
#pragma unroll
    for (int m = 0; m < 4; ++m)
      af[m] = *(const short8*)&As[(wr * 64 + m * 16 + lrow) * 32 + lgrp * 8];
#pragma unroll
    for (int n = 0; n < 4; ++n)
      bf[n] = *(const short8*)&Bs[(wc * 64 + n * 16 + lrow) * 32 + lgrp * 8];
#pragma unroll
    for (int m = 0; m < 4; ++m)
#pragma unroll
      for (int n = 0; n < 4; ++n)
        acc[m][n] = __builtin_amdgcn_mfma_f32_16x16x32_bf16(af[m], bf[n], acc[m][n], 0, 0, 0);
    __syncthreads();
  }

  if (MODE == 0) {
#pragma unroll
    for (int n = 0; n < 4; ++n) {
      const int c = (int)col0 + wc * 64 + n * 16 + lrow;
      const float bs = bias[c];
      const int sect = c >> 10;            // 0=Q 1=K 2=V
      const int h = (c & 1023) >> 6;
      const int d = c & 63;
      unsigned short* dst = sect == 0 ? q_out : (sect == 1 ? k_out : v_out);
      const float scl = sect == 0 ? 0.125f : 1.0f;  // fold 1/sqrt(64) into Q
#pragma unroll
      for (int m = 0; m < 4; ++m) {
#pragma unroll
        for (int i = 0; i < 4; ++i) {
          const long r = row0 + wr * 64 + m * 16 + lgrp * 4 + i;
          const long b = r >> 11;          // r / 2048
          const long t = r & 2047;
          const float val = (acc[m][n][i] + bs) * scl;
          dst[((b * NH + h) * T_LEN + t) * HD + d] = f2bf(val);
        }
      }
    }
  } else {
#pragma unroll
    for (int n = 0; n < 4; ++n) {
      const int c = (int)col0 + wc * 64 + n * 16 + lrow;
      const float bs = bias[c];
#pragma unroll
      for (int m = 0; m < 4; ++m) {
#pragma unroll
        for (int i = 0; i < 4; ++i) {
          const long r = row0 + wr * 64 + m * 16 + lgrp * 4 + i;
          f_out[r * (long)N + c] = acc[m][n][i] + bs;
        }
      }
    }
  }
}

// ------- flash attention v4: KV-split across 4 waves, swapped QK^T, hoisted loads -------
// Block = (bh, qt): 32 q-rows, 4 waves split the KV steps (wave w: steps w, w+4, ...).
// Lane-local softmax (swapped QK^T), reg-direct PV via 16x16x16 MFMA.
// Per-wave online-softmax partials combined via LDS in the epilogue.
// Grid is 1-D, XCD-clustered: xcd = bid&7 serves heads 4*xcd..4*xcd+3 (KV fits XCD L2).
__global__ __launch_bounds__(256) void attn_fwd(
    const unsigned short* __restrict__ Qb,
    const unsigned short* __restrict__ Kb,
    const unsigned short* __restrict__ Vt,
    unsigned short* __restrict__ attn) {
  __shared__ float o_lds[4][32][68];      // [wave][q][d] padded stride 68
  __shared__ float mshare[4][2][16];
  __shared__ float sshare[4][2][16];
  const int bid = (int)blockIdx.x;
  const int xcd = bid & 7;
  const int j = bid >> 3;
  const int bh = xcd * 4 + (j & 3);       // 4 heads per XCD -> KV in XCD L2
  const int qt = j >> 2;                  // 0..63
  const int b = bh >> 4, h = bh & 15;
  const int wid = (int)threadIdx.x >> 6;
  const int lane = (int)threadIdx.x & 63;
  const int lrow = lane & 15, lgrp = lane >> 4;
  const int q0 = qt * 32;
  const int nsteps = (q0 + 32 + 63) >> 6; // ceil((q0+32)/64)

  const unsigned short* Qh = Qb + (long)bh * T_LEN * HD;
  const unsigned short* Kh = Kb + (long)bh * T_LEN * HD;
  const unsigned short* Vh = Vt + (long)bh * HD * T_LEN;

  // Q fragments (B operand of swapped QK^T): [qsub][kk]
  short8 aq[2][2];
#pragma unroll
  for (int qs = 0; qs < 2; ++qs)
#pragma unroll
    for (int kk = 0; kk < 2; ++kk)
      aq[qs][kk] = *(const short8*)(Qh + (long)(q0 + qs * 16 + lrow) * HD + kk * 32 + lgrp * 8);

  float m_i[2] = {-1e30f, -1e30f};
  float s_i[2] = {0.f, 0.f};
  floatx4 o[2][4];                        // O[q=16qs+4lg+i][d=16d0+lrow]
#pragma unroll
  for (int qs = 0; qs < 2; ++qs)
#pragma unroll
    for (int d0 = 0; d0 < 4; ++d0) o[qs][d0] = (floatx4){0.f, 0.f, 0.f, 0.f};

  for (int st = wid; st < nsteps; st += 4) {
    const int s0 = st * 64;
    // ---- hoisted K loads: 8 independent 16B loads pipeline together ----
    short8 kf[4][2];
#pragma unroll
    for (int sc = 0; sc < 4; ++sc)
#pragma unroll
      for (int kk = 0; kk < 2; ++kk)
        kf[sc][kk] = *(const short8*)(Kh + (long)(s0 + sc * 16 + lrow) * HD + kk * 32 + lgrp * 8);
    // ---- hoisted V loads: 16 independent 8B loads; latency hides under softmax ----
    s16x4 vb[4][4];                       // [d0][sc]
#pragma unroll
    for (int d0 = 0; d0 < 4; ++d0)
#pragma unroll
      for (int sc = 0; sc < 4; ++sc)
        vb[d0][sc] = *(const s16x4*)(Vh + (long)(d0 * 16 + lrow) * T_LEN + s0 + sc * 16 + lgrp * 4);
    // ---- QK^T (swapped): sf[qs][sc][i] = S[q=q0+16qs+lrow][s=s0+16sc+4lg+i] ----
    floatx4 sf[2][4];
#pragma unroll
    for (int qs = 0; qs < 2; ++qs)
#pragma unroll
      for (int sc = 0; sc < 4; ++sc) sf[qs][sc] = (floatx4){0.f, 0.f, 0.f, 0.f};
#pragma unroll
    for (int sc = 0; sc < 4; ++sc) {
#pragma unroll
      for (int kk = 0; kk < 2; ++kk) {
        sf[0][sc] = __builtin_amdgcn_mfma_f32_16x16x32_bf16(kf[sc][kk], aq[0][kk], sf[0][sc], 0, 0, 0);
        sf[1][sc] = __builtin_amdgcn_mfma_f32_16x16x32_bf16(kf[sc][kk], aq[1][kk], sf[1][sc], 0, 0, 0);
      }
    }
    // ---- causal mask (diagonal step only): q = row-space lrow, s = col-space ----
    if (s0 + 64 > q0) {
#pragma unroll
      for (int qs = 0; qs < 2; ++qs) {
        const int q = q0 + qs * 16 + lrow;
#pragma unroll
        for (int sc = 0; sc < 4; ++sc) {
#pragma unroll
          for (int i = 0; i < 4; ++i) {
            const int s = s0 + sc * 16 + lgrp * 4 + i;
            if (s > q) sf[qs][sc][i] = -1e30f;
          }
        }
      }
    }
    // ---- online softmax: row lane-local (16 vals) + 2 shfl_xor ----
    s16x4 pa[2][4];
#pragma unroll
    for (int qs = 0; qs < 2; ++qs) {
      float m0 = fmaxf(fmaxf(sf[qs][0][0], sf[qs][0][1]), fmaxf(sf[qs][0][2], sf[qs][0][3]));
      float m1 = fmaxf(fmaxf(sf[qs][1][0], sf[qs][1][1]), fmaxf(sf[qs][1][2], sf[qs][1][3]));
      float m2 = fmaxf(fmaxf(sf[qs][2][0], sf[qs][2][1]), fmaxf(sf[qs][2][2], sf[qs][2][3]));
      float m3 = fmaxf(fmaxf(sf[qs][3][0], sf[qs][3][1]), fmaxf(sf[qs][3][2], sf[qs][3][3]));
      float m0123 = fmaxf(fmaxf(m0, m1), fmaxf(m2, m3));
      m0123 = fmaxf(m0123, __shfl_xor(m0123, 16));
      m0123 = fmaxf(m0123, __shfl_xor(m0123, 32));
      const float mnew = fmaxf(m_i[qs], m0123);
      const float scale = __expf(m_i[qs] - mnew);
      float rs = 0.f;
#pragma unroll
      for (int sc = 0; sc < 4; ++sc) {
#pragma unroll
        for (int i = 0; i < 4; ++i) {
          const float pv = __expf(sf[qs][sc][i] - mnew);
          sf[qs][sc][i] = pv;
          rs += pv;
        }
      }
      rs += __shfl_xor(rs, 16);
      rs += __shfl_xor(rs, 32);
      m_i[qs] = mnew;
      s_i[qs] = s_i[qs] * scale + rs;
      // broadcast scale from lrow-space to (lg,i)-space, rescale O
#pragma unroll
      for (int i = 0; i < 4; ++i) {
        const float sbc = __shfl(scale, 4 * lgrp + i);
#pragma unroll
        for (int d0 = 0; d0 < 4; ++d0) o[qs][d0][i] *= sbc;
      }
      // pack P to bf16 A-fragments of the 16x16x16 MFMA (layout matches directly)
#pragma unroll
      for (int sc = 0; sc < 4; ++sc) {
        union { unsigned u[2]; s16x4 v; } tmp;
        tmp.u[0] = cvt_pk_bf16(sf[qs][sc][0], sf[qs][sc][1]);
        tmp.u[1] = cvt_pk_bf16(sf[qs][sc][2], sf[qs][sc][3]);
        pa[qs][sc] = tmp.v;
      }
    }
    // ---- PV: O[q][d] += sum_sc P_frag[sc] x V_frag[sc] (16x16x16) ----
#pragma unroll
    for (int d0 = 0; d0 < 4; ++d0) {
#pragma unroll
      for (int sc = 0; sc < 4; ++sc) {
        o[0][d0] = mfma16(pa[0][sc], vb[d0][sc], o[0][d0]);
        o[1][d0] = mfma16(pa[1][sc], vb[d0][sc], o[1][d0]);
      }
    }
  }

  // ---- combine the 4 per-wave partials ----
  mshare[wid][0][lrow] = m_i[0];          // uniform across lgrp (same value, same addr)
  mshare[wid][1][lrow] = m_i[1];
  __syncthreads();
#pragma unroll
  for (int qs = 0; qs < 2; ++qs) {
    const float gm = fmaxf(fmaxf(mshare[0][qs][lrow], mshare[1][qs][lrow]),
                           fmaxf(mshare[2][qs][lrow], mshare[3][qs][lrow]));
    const float f = __expf(m_i[qs] - gm);
    sshare[wid][qs][lrow] = s_i[qs] * f;
#pragma unroll
    for (int i = 0; i < 4; ++i) {
      const float fb = __shfl(f, 4 * lgrp + i);
#pragma unroll
      for (int d0 = 0; d0 < 4; ++d0)
        o_lds[wid][qs * 16 + lgrp * 4 + i][d0 * 16 + lrow] = o[qs][d0][i] * fb;
    }
  }
  __syncthreads();
  // ---- final reduce + write: thread t -> q = t>>3, 8 d-values ----
  const int t = (int)threadIdx.x;
  const int q = t >> 3;
  const int d8 = (t & 7) * 8;
  const int qss = q >> 4, qr = q & 15;
  const float S = sshare[0][qss][qr] + sshare[1][qss][qr] +
                  sshare[2][qss][qr] + sshare[3][qss][qr];
  const float invS = 1.0f / S;
  short8 wv;
#pragma unroll
  for (int jj = 0; jj < 8; ++jj) {
    const float acc = o_lds[0][q][d8 + jj] + o_lds[1][q][d8 + jj] +
                      o_lds[2][q][d8 + jj] + o_lds[3][q][d8 + jj];
    wv[jj] = (short)f2bf(acc * invS);
  }
  *(short8*)(attn + (long)(b * T_LEN + q0 + q) * C_DIM + h * HD + d8) = wv;
}

extern "C" void kernel_launch(void* const* d_in, const int* in_sizes, int n_in,
                              void* d_out, int out_size, void* d_ws, size_t ws_size,
                              hipStream_t stream) {
  const float* x     = (const float*)d_in[0];
  const float* Wqkv  = (const float*)d_in[1];
  const float* bqkv  = (const float*)d_in[2];
  const float* Wproj = (const float*)d_in[3];
  const float* bproj = (const float*)d_in[4];
  float* out = (float*)d_out;
  char* ws = (char*)d_ws;
  const size_t MB = 1024 * 1024;
  unsigned short* Qb     = (unsigned short*)(ws + 0 * MB);   // [B,N,T,D] bf16, pre-scaled 1/8
  unsigned short* Kb     = (unsigned short*)(ws + 8 * MB);   // [B,N,T,D]
  unsigned short* Vb     = (unsigned short*)(ws + 16 * MB);  // [B,N,T,D]
  unsigned short* Vt     = (unsigned short*)(ws + 24 * MB);  // [B,N,D,T]
  unsigned short* attn   = (unsigned short*)(ws + 32 * MB);  // [B,T,C]
  unsigned short* xbf    = (unsigned short*)(ws + 40 * MB);  // [B*T,C]
  unsigned short* Wqkvt  = (unsigned short*)(ws + 48 * MB);  // [3C,C]
  unsigned short* Wprojt = (unsigned short*)(ws + 54 * MB);  // [C,C]

  cast_x<<<4096, 256, 0, stream>>>(x, xbf);
  transpose_cast<<<dim3(48, 16), 256, 0, stream>>>(Wqkv, Wqkvt, 1024, 3072);
  transpose_cast<<<dim3(16, 16), 256, 0, stream>>>(Wproj, Wprojt, 1024, 1024);
  gemm_bt<0><<<dim3(24, 32), 256, 0, stream>>>(xbf, Wqkvt, bqkv, 4096, 3072, 1024,
                                               Qb, Kb, Vb, nullptr);
  vtrans<<<dim3(32, 32), 256, 0, stream>>>(Vb, Vt);
  attn_fwd<<<2048, 256, 0, stream>>>(Qb, Kb, Vt, attn);
  gemm_bt<1><<<dim3(8, 32), 256, 0, stream>>>(attn, Wprojt, bproj, 4096, 1024, 1024,
                                              nullptr, nullptr, nullptr, out);
}